// Round 23
// baseline (390.286 us; speedup 1.0000x reference)
//
#include <hip/hip_runtime.h>
#include <hip/hip_bf16.h>

static constexpr int Bn = 2, Tn = 2048, Cn = 1024, Hn = 16, HSn = 64;
static constexpr int Mrows = Bn * Tn;                 // 4096
static constexpr size_t PL = (size_t)Bn * Hn * Tn * HSn;  // one qkv plane (4.19M)

typedef __attribute__((ext_vector_type(8))) short short8;
typedef __attribute__((ext_vector_type(4))) float f32x4;

__device__ __forceinline__ unsigned short f2bf(float f) {
  __hip_bfloat16 h = __float2bfloat16(f);
  return *reinterpret_cast<unsigned short*>(&h);
}

__device__ __forceinline__ float fexp2(float x) {
  return __builtin_amdgcn_exp2f(x);
}

__device__ __forceinline__ void gload_lds16(const void* g, void* l) {
  __builtin_amdgcn_global_load_lds(
      (const __attribute__((address_space(1))) void*)g,
      (__attribute__((address_space(3))) void*)l, 16, 0, 0);
}

// qscale folded into Q plane at GEMM epilogue: (1/sqrt(64)) * log2(e)
#define QSC 0.18033688011112042591999058512524f

// device-scope grid barrier; safe: LDS 114688B caps 1 block/CU and grid=256
// <= 256 CUs, so all blocks are co-resident by capacity.
__device__ __forceinline__ void grid_barrier(unsigned* bar, int slot) {
  __threadfence();                       // release (all threads)
  __syncthreads();
  if (threadIdx.x == 0) {
    atomicAdd(&bar[slot], 1u);
    while (atomicAdd(&bar[slot], 0u) < 256u) __builtin_amdgcn_s_sleep(8);
  }
  __syncthreads();
  __threadfence();                       // acquire (all threads)
}

// ---------------------------------------------------------------------------
// Fused: prep -> QKV GEMM -> attention -> proj GEMM, 256 blocks x 512 thr.
// ---------------------------------------------------------------------------
__global__ __launch_bounds__(512, 1) void fused_all(
    const float* __restrict__ x,
    const float* __restrict__ Wa, const float* __restrict__ ba,
    const float* __restrict__ Wp, const float* __restrict__ bp,
    unsigned short* __restrict__ xb, unsigned short* __restrict__ Wab,
    unsigned short* __restrict__ Wpb, unsigned short* __restrict__ qkv,
    unsigned short* __restrict__ y, float* __restrict__ out,
    unsigned* __restrict__ bar)
{
  __shared__ alignas(16) unsigned char lds[114688];
  const int blk = blockIdx.x, tid = threadIdx.x;
  const int wave = tid >> 6, lane = tid & 63;
  const int a = lane & 15, h = lane >> 4;

  //======================= phase 0: prep =======================
  {
    const float4* xs = (const float4*)x;
    ushort4* xd = (ushort4*)xb;
    for (int i = blk * 512 + tid; i < Mrows * Cn / 4; i += 256 * 512) {
      float4 v = xs[i];
      ushort4 o;
      o.x = f2bf(v.x); o.y = f2bf(v.y); o.z = f2bf(v.z); o.w = f2bf(v.w);
      xd[i] = o;
    }
    // transposes: 4096 32x32 tiles, 2 per block per pass, 8 passes
    float* tile = (float*)(lds + (tid >> 8) * 4224);   // [32][33] floats
    const int t256 = tid & 255;
    const int tx = t256 & 31, ty = t256 >> 5;          // 32 x 8
    for (int pass = 0; pass < 8; ++pass) {
      int tb = blk * 16 + pass * 2 + (tid >> 8);
      const float* src; unsigned short* dst; int Cc, tnum;
      if (tb < 3072) { src = Wa; dst = Wab; Cc = 3 * Cn; tnum = tb; }
      else           { src = Wp; dst = Wpb; Cc = Cn;     tnum = tb - 3072; }
      const int nbx = Cc / 32;
      const int bx = tnum % nbx, by = tnum / nbx;
      const int c0 = bx * 32, r0 = by * 32;
      #pragma unroll
      for (int i = 0; i < 4; ++i)
        tile[(ty + 8 * i) * 33 + tx] = src[(size_t)(r0 + ty + 8 * i) * Cc + c0 + tx];
      __syncthreads();
      #pragma unroll
      for (int i = 0; i < 4; ++i)
        dst[(size_t)(c0 + ty + 8 * i) * Cn + r0 + tx] = f2bf(tile[tx * 33 + ty + 8 * i]);
      __syncthreads();
    }
  }
  grid_barrier(bar, 0);

  //======================= phase 1: QKV GEMM (R15) =======================
  {
    constexpr int NSTEP = 16;          // K=1024 / BK=64
    constexpr int AF = 32, BF = 24;    // frags per buffer
    const int wr = wave >> 2, wc = wave & 3;
    const int swz = (blk & 7) * 32 + (blk >> 3);
    const int bx = swz & 15, by = swz >> 4;
    const int tM = by * 256, tN = bx * 192;
    const int K = Cn;

    auto STAGE = [&](int buf, int k0) {
      #pragma unroll
      for (int i = 0; i < 7; ++i) {
        int f = wave * 7 + i;
        const unsigned short* g;
        int off;
        if (f < AF) {
          int mg = f >> 1, ks = f & 1;
          g = xb + (size_t)(tM + mg * 16 + (lane & 15)) * K + k0 + ks * 32 + (lane >> 4) * 8;
          off = f * 1024;
        } else {
          int fg = f - AF;
          int ng = fg >> 1, ks = fg & 1;
          g = Wab + (size_t)(tN + ng * 16 + (lane & 15)) * K + k0 + ks * 32 + (lane >> 4) * 8;
          off = AF * 1024 + fg * 1024;
        }
        gload_lds16(g, &lds[buf * 57344 + off]);
      }
    };

    f32x4 acc[8][3] = {};

    STAGE(0, 0);
    STAGE(1, 64);

    for (int t = 0; t < NSTEP; ++t) {
      if (t == NSTEP - 1)
        asm volatile("s_waitcnt vmcnt(0)" ::: "memory");
      else
        asm volatile("s_waitcnt vmcnt(7)" ::: "memory");
      __builtin_amdgcn_s_barrier();

      const int cur = t & 1;
      const unsigned char* base = &lds[cur * 57344];
      short8 af[8][2], bfr[3][2];
      #pragma unroll
      for (int ks = 0; ks < 2; ++ks) {
        #pragma unroll
        for (int m = 0; m < 8; ++m)
          af[m][ks] = *(const short8*)&base[((wr * 8 + m) * 2 + ks) * 1024 + lane * 16];
        #pragma unroll
        for (int n = 0; n < 3; ++n)
          bfr[n][ks] = *(const short8*)&base[AF * 1024 + ((wc * 3 + n) * 2 + ks) * 1024 + lane * 16];
      }
      asm volatile("s_waitcnt lgkmcnt(0)" ::: "memory");
      __builtin_amdgcn_sched_barrier(0);
      __builtin_amdgcn_s_barrier();

      if (t + 2 < NSTEP) STAGE(cur, (t + 2) * 64);

      __builtin_amdgcn_s_setprio(1);
      #pragma unroll
      for (int ks = 0; ks < 2; ++ks)
        #pragma unroll
        for (int m = 0; m < 8; ++m)
          #pragma unroll
          for (int n = 0; n < 3; ++n)
            acc[m][n] = __builtin_amdgcn_mfma_f32_16x16x32_bf16(af[m][ks], bfr[n][ks], acc[m][n], 0, 0, 0);
      __builtin_amdgcn_s_setprio(0);
    }

    const int hq = lane >> 4;
    #pragma unroll
    for (int m = 0; m < 8; ++m) {
      #pragma unroll
      for (int n = 0; n < 3; ++n) {
        int c = tN + wc * 48 + n * 16 + a;
        float bv = ba[c];
        int which = c >> 10;
        int cc = c & 1023, hh = cc >> 6, d = cc & 63;
        int row0 = tM + wr * 128 + m * 16 + hq * 4;
        int b = row0 >> 11, t0 = row0 & 2047;
        int bh = b * Hn + hh;
        if (which == 2) {
          ushort4 pk;
          pk.x = f2bf(acc[m][n][0] + bv);
          pk.y = f2bf(acc[m][n][1] + bv);
          pk.z = f2bf(acc[m][n][2] + bv);
          pk.w = f2bf(acc[m][n][3] + bv);
          *(ushort4*)&qkv[2 * PL + ((size_t)bh * HSn + d) * Tn + t0] = pk;
        } else {
          float sc = (which == 0) ? QSC : 1.0f;
          #pragma unroll
          for (int r = 0; r < 4; ++r) {
            float v = (acc[m][n][r] + bv) * sc;
            qkv[(size_t)which * PL + ((size_t)bh * Tn + t0 + r) * HSn + d] = f2bf(v);
          }
        }
      }
    }
  }
  grid_barrier(bar, 1);

  //======================= phase 2: attention =======================
  // 2 logical 4-wave blocks per physical block (same yb -> aligned barriers)
  {
    const int yb = blk & 15;
    const int half = wave >> 2;
    const int bh = ((blk >> 4) << 1) | half;
    const int w4 = wave & 3;
    unsigned char* L = lds + half * 41984;
    const unsigned short* Qp = qkv + (size_t)bh * Tn * HSn;
    const unsigned short* Kp = qkv + PL + (size_t)bh * Tn * HSn;
    const unsigned short* Vp = qkv + 2 * PL + (size_t)bh * HSn * Tn;
    const int pbase = w4 * 2304;
    const int qglob = w4 * 16 + a;
    const int b = bh >> 4, hd = bh & 15;

    auto STAGE_K = [&](int kb, int kv0) {
      #pragma unroll
      for (int i = 0; i < 2; ++i) {
        int r8 = w4 * 16 + i * 8;
        int row = r8 + (lane >> 3);
        int ch = (lane & 7) ^ (row & 7);
        gload_lds16(Kp + (size_t)(kv0 + row) * HSn + ch * 8,
                    &L[9216 + kb * 8192 + r8 * 128]);
      }
    };
    auto STAGE_V = [&](int vb, int kv0) {
      #pragma unroll
      for (int i = 0; i < 2; ++i) {
        int r8 = w4 * 16 + i * 8;
        int row = r8 + (lane >> 3);
        int ch = (lane & 7) ^ (row & 7);
        gload_lds16(Vp + (size_t)row * Tn + kv0 + ch * 8,
                    &L[25600 + vb * 8192 + r8 * 128]);
      }
    };

    short8 ones;
    #pragma unroll
    for (int j = 0; j < 8; ++j) ones[j] = (short)0x3F80;   // bf16 1.0

    for (int ph = 0; ph < 2; ++ph) {
      const int qt = ph ? (31 - yb) : yb;
      const int q0 = qt * 64;

      // Q directly global -> registers (16B contiguous per lane, L2-hot)
      short8 qf[2];
      #pragma unroll
      for (int ks = 0; ks < 2; ++ks)
        qf[ks] = *(const short8*)(Qp + (size_t)(q0 + qglob) * HSn + ks * 32 + h * 8);

      STAGE_K(0, 0);
      STAGE_V(0, 0);
      if (qt >= 1) {
        STAGE_K(1, 64);
        STAGE_V(1, 64);
      }

      f32x4 o[4] = {};
      f32x4 lacc = {};

      for (int t = 0; t <= qt; ++t) {
        const int kb = t & 1;
        if (t == qt)
          asm volatile("s_waitcnt vmcnt(0)" ::: "memory");
        else
          asm volatile("s_waitcnt vmcnt(4)" ::: "memory");
        __builtin_amdgcn_s_barrier();

        const int kbase = 9216 + kb * 8192;
        const int vbase = 25600 + kb * 8192;

        f32x4 s[4] = {};
        __builtin_amdgcn_s_setprio(1);
        #pragma unroll
        for (int ks = 0; ks < 2; ++ks)
          #pragma unroll
          for (int n = 0; n < 4; ++n) {
            int kr = n * 16 + a;
            int ch = (ks * 4 + h) ^ (kr & 7);
            short8 kf = *(const short8*)&L[kbase + kr * 128 + ch * 16];
            s[n] = __builtin_amdgcn_mfma_f32_16x16x32_bf16(kf, qf[ks], s[n], 0, 0, 0);
          }
        __builtin_amdgcn_s_setprio(0);

        if (t == qt) {
          #pragma unroll
          for (int n = 0; n < 4; ++n)
            #pragma unroll
            for (int r = 0; r < 4; ++r)
              if ((n * 16 + h * 4 + r) > qglob) s[n][r] = -1e30f;
        }

        #pragma unroll
        for (int n = 0; n < 4; ++n)
          #pragma unroll
          for (int r = 0; r < 4; ++r) s[n][r] = fexp2(s[n][r]);

        #pragma unroll
        for (int n = 0; n < 4; ++n) {
          uint2 w2;
          w2.x = (unsigned)f2bf(s[n][0]) | ((unsigned)f2bf(s[n][1]) << 16);
          w2.y = (unsigned)f2bf(s[n][2]) | ((unsigned)f2bf(s[n][3]) << 16);
          *(uint2*)&L[pbase + (a * 36 + n * 8 + h * 2) * 4] = w2;
        }

        __builtin_amdgcn_s_setprio(1);
        #pragma unroll
        for (int ks = 0; ks < 2; ++ks) {
          short8 pa = *(const short8*)&L[pbase + (a * 36 + ks * 16 + h * 4) * 4];
          lacc = __builtin_amdgcn_mfma_f32_16x16x32_bf16(pa, ones, lacc, 0, 0, 0);
          #pragma unroll
          for (int n = 0; n < 4; ++n) {
            int d = n * 16 + a;
            int ch = (ks * 4 + h) ^ (d & 7);
            short8 vf = *(const short8*)&L[vbase + d * 128 + ch * 16];
            o[n] = __builtin_amdgcn_mfma_f32_16x16x32_bf16(pa, vf, o[n], 0, 0, 0);
          }
        }
        __builtin_amdgcn_s_setprio(0);

        __builtin_amdgcn_s_barrier();
        if (t + 2 <= qt) {
          STAGE_K(kb, (t + 2) * 64);
          STAGE_V(kb, (t + 2) * 64);
        }
      }

      f32x4 inv;
      #pragma unroll
      for (int r = 0; r < 4; ++r) inv[r] = 1.0f / lacc[r];
      #pragma unroll
      for (int n = 0; n < 4; ++n)
        #pragma unroll
        for (int r = 0; r < 4; ++r) {
          int tr = q0 + w4 * 16 + 4 * h + r;
          int col = hd * 64 + n * 16 + a;
          y[((size_t)(b * Tn + tr)) * Cn + col] = f2bf(o[n][r] * inv[r]);
        }
    }
  }
  grid_barrier(bar, 2);

  //======================= phase 3: proj GEMM =======================
  // 2 logical 4-wave blocks per physical block (same bx -> aligned barriers)
  {
    constexpr int AF = 8, BF = 4;      // 128x64 tile frags
    const int bx = blk & 15;
    const int half = wave >> 2;
    const int by = ((blk >> 4) << 1) | half;
    const int w4 = wave & 3;
    const int wr = w4 >> 1, wc = w4 & 1;
    unsigned char* L = lds + half * 24576;
    const int tM = by * 128, tN = bx * 64;
    const int K = Cn;

    auto STAGE = [&](int buf, int k0) {
      #pragma unroll
      for (int i = 0; i < 3; ++i) {
        int f = w4 * 3 + i;
        const unsigned short* g;
        if (f < AF)
          g = y + (size_t)(tM + f * 16 + (lane & 15)) * K + k0 + (lane >> 4) * 8;
        else
          g = Wpb + (size_t)(tN + (f - AF) * 16 + (lane & 15)) * K + k0 + (lane >> 4) * 8;
        gload_lds16(g, &L[buf * 12288 + f * 1024]);
      }
    };

    f32x4 acc[4][2] = {};

    STAGE(0, 0);
    for (int t = 0, k0 = 0;; ++t, k0 += 32) {
      const int cur = t & 1;
      if (k0 + 32 < K) {
        STAGE(cur ^ 1, k0 + 32);
        asm volatile("s_waitcnt vmcnt(3)" ::: "memory");
      } else {
        asm volatile("s_waitcnt vmcnt(0)" ::: "memory");
      }
      __builtin_amdgcn_s_barrier();

      const unsigned char* base = &L[cur * 12288];
      short8 af[4], bfr[2];
      #pragma unroll
      for (int m = 0; m < 4; ++m)
        af[m] = *(const short8*)&base[(wr * 4 + m) * 1024 + lane * 16];
      #pragma unroll
      for (int n = 0; n < 2; ++n)
        bfr[n] = *(const short8*)&base[(AF + wc * 2 + n) * 1024 + lane * 16];
      #pragma unroll
      for (int m = 0; m < 4; ++m)
        #pragma unroll
        for (int n = 0; n < 2; ++n)
          acc[m][n] = __builtin_amdgcn_mfma_f32_16x16x32_bf16(af[m], bfr[n], acc[m][n], 0, 0, 0);

      __builtin_amdgcn_s_barrier();
      if (k0 + 32 >= K) break;
    }

    const int hq = lane >> 4;
    #pragma unroll
    for (int m = 0; m < 4; ++m) {
      #pragma unroll
      for (int n = 0; n < 2; ++n) {
        int c = tN + wc * 32 + n * 16 + a;
        float bv = bp[c];
        int r0 = tM + wr * 64 + m * 16 + hq * 4;
        #pragma unroll
        for (int r = 0; r < 4; ++r)
          out[(size_t)(r0 + r) * Cn + c] = acc[m][n][r] + bv;
      }
    }
  }
}

// ---------------------------------------------------------------------------
extern "C" void kernel_launch(void* const* d_in, const int* in_sizes, int n_in,
                              void* d_out, int out_size, void* d_ws, size_t ws_size,
                              hipStream_t stream) {
  const float* x      = (const float*)d_in[0];
  const float* W_attn = (const float*)d_in[1];
  const float* b_attn = (const float*)d_in[2];
  const float* W_proj = (const float*)d_in[3];
  const float* b_proj = (const float*)d_in[4];
  float* out = (float*)d_out;

  unsigned short* xb  = (unsigned short*)d_ws;          // [4096][1024]
  unsigned short* Wab = xb + (size_t)Mrows * Cn;        // [3072][1024]
  unsigned short* Wpb = Wab + (size_t)3 * Cn * Cn;      // [1024][1024]
  unsigned short* qkv = Wpb + (size_t)Cn * Cn;          // 3 planes of PL
  unsigned short* y   = qkv + 3 * PL;                   // [4096][1024]
  unsigned* bar       = (unsigned*)(y + (size_t)Mrows * Cn);

  hipMemsetAsync(bar, 0, 4 * sizeof(unsigned), stream);

  fused_all<<<256, 512, 0, stream>>>(
      x, W_attn, b_attn, W_proj, b_proj,
      xb, Wab, Wpb, qkv, y, out, bar);
}

// Round 24
// 108.635 us; speedup vs baseline: 3.5926x; 3.5926x over previous
//
#include <hip/hip_runtime.h>
#include <hip/hip_bf16.h>

static constexpr int Bn = 2, Tn = 2048, Cn = 1024, Hn = 16, HSn = 64;
static constexpr int Mrows = Bn * Tn;                 // 4096
static constexpr size_t PL = (size_t)Bn * Hn * Tn * HSn;  // one qkv plane (4.19M)

typedef __attribute__((ext_vector_type(8))) short short8;
typedef __attribute__((ext_vector_type(4))) float f32x4;

__device__ __forceinline__ unsigned short f2bf(float f) {
  __hip_bfloat16 h = __float2bfloat16(f);
  return *reinterpret_cast<unsigned short*>(&h);
}

__device__ __forceinline__ float fexp2(float x) {
  return __builtin_amdgcn_exp2f(x);
}

__device__ __forceinline__ void gload_lds16(const void* g, void* l) {
  __builtin_amdgcn_global_load_lds(
      (const __attribute__((address_space(1))) void*)g,
      (__attribute__((address_space(3))) void*)l, 16, 0, 0);
}

// qscale folded into Q plane at GEMM epilogue: (1/sqrt(64)) * log2(e)
#define QSC 0.18033688011112042591999058512524f

// ---------------------------------------------------------------------------
// merged prep kernel
// ---------------------------------------------------------------------------
__global__ __launch_bounds__(256) void prep_all(
    const float* __restrict__ x, unsigned short* __restrict__ xb,
    const float* __restrict__ Wa, unsigned short* __restrict__ Wab,
    const float* __restrict__ Wp, unsigned short* __restrict__ Wpb)
{
  const int bid = blockIdx.x, tid = threadIdx.x;
  if (bid < 4096) {
    int i = bid * 256 + tid;
    float4 v = ((const float4*)x)[i];
    ushort4 o;
    o.x = f2bf(v.x); o.y = f2bf(v.y); o.z = f2bf(v.z); o.w = f2bf(v.w);
    ((ushort4*)xb)[i] = o;
    return;
  }
  __shared__ float tile[32][33];
  const float* src; unsigned short* dst; int R, Cc, tb;
  if (bid < 4096 + 3072) { src = Wa; dst = Wab; R = Cn; Cc = 3 * Cn; tb = bid - 4096; }
  else                   { src = Wp; dst = Wpb; R = Cn; Cc = Cn;     tb = bid - 4096 - 3072; }
  const int nbx = Cc / 32;
  const int bx = tb % nbx, by = tb / nbx;
  const int tx = tid & 31, ty = tid >> 5;
  const int c0 = bx * 32, r0 = by * 32;
  #pragma unroll
  for (int i = 0; i < 4; ++i)
    tile[ty + 8 * i][tx] = src[(size_t)(r0 + ty + 8 * i) * Cc + c0 + tx];
  __syncthreads();
  #pragma unroll
  for (int i = 0; i < 4; ++i)
    dst[(size_t)(c0 + ty + 8 * i) * R + r0 + tx] = f2bf(tile[tx][ty + 8 * i]);
}

// ---------------------------------------------------------------------------
// QKV GEMM (R15 winner): 256x192 tile -> grid 256 (1 per CU), BK=64,
// 8 waves, LDS 2x56KB, 2-deep prefetch counted vmcnt(7), XCD-swizzled.
// ---------------------------------------------------------------------------
__global__ __launch_bounds__(512) void gemmQKV(
    const unsigned short* __restrict__ A, const unsigned short* __restrict__ Bt,
    const float* __restrict__ bias, unsigned short* __restrict__ qkv, int K)
{
  constexpr int NSTEP = 1024 / 64;     // 16 K-steps
  constexpr int AF = 32;               // 16 mg x 2 ks
  constexpr int BF = 24;               // 12 ng x 2 ks
  __shared__ alignas(16) unsigned char lds[2][(AF + BF) * 1024];

  const int tid = threadIdx.x, wave = tid >> 6, lane = tid & 63;
  const int wr = wave >> 2, wc = wave & 3;            // 2 x 4 wave grid
  const int orig = blockIdx.x;
  const int swz = (orig & 7) * 32 + (orig >> 3);      // XCD swizzle
  const int bx = swz & 15, by = swz >> 4;
  const int tM = by * 256, tN = bx * 192;

  auto STAGE = [&](int buf, int k0) {
    #pragma unroll
    for (int i = 0; i < 7; ++i) {
      int f = wave * 7 + i;
      const unsigned short* g;
      int off;
      if (f < AF) {
        int mg = f >> 1, ks = f & 1;
        g = A + (size_t)(tM + mg * 16 + (lane & 15)) * K + k0 + ks * 32 + (lane >> 4) * 8;
        off = f * 1024;
      } else {
        int fg = f - AF;
        int ng = fg >> 1, ks = fg & 1;
        g = Bt + (size_t)(tN + ng * 16 + (lane & 15)) * K + k0 + ks * 32 + (lane >> 4) * 8;
        off = AF * 1024 + fg * 1024;
      }
      gload_lds16(g, &lds[buf][off]);
    }
  };

  f32x4 acc[8][3] = {};

  STAGE(0, 0);
  STAGE(1, 64);

  for (int t = 0; t < NSTEP; ++t) {
    if (t == NSTEP - 1)
      asm volatile("s_waitcnt vmcnt(0)" ::: "memory");
    else
      asm volatile("s_waitcnt vmcnt(7)" ::: "memory");
    __builtin_amdgcn_s_barrier();

    const int cur = t & 1;
    short8 af[8][2], bfr[3][2];
    #pragma unroll
    for (int ks = 0; ks < 2; ++ks) {
      #pragma unroll
      for (int m = 0; m < 8; ++m)
        af[m][ks] = *(const short8*)&lds[cur][((wr * 8 + m) * 2 + ks) * 1024 + lane * 16];
      #pragma unroll
      for (int n = 0; n < 3; ++n)
        bfr[n][ks] = *(const short8*)&lds[cur][AF * 1024 + ((wc * 3 + n) * 2 + ks) * 1024 + lane * 16];
    }
    asm volatile("s_waitcnt lgkmcnt(0)" ::: "memory");
    __builtin_amdgcn_sched_barrier(0);
    __builtin_amdgcn_s_barrier();

    if (t + 2 < NSTEP) STAGE(cur, (t + 2) * 64);

    __builtin_amdgcn_s_setprio(1);
    #pragma unroll
    for (int ks = 0; ks < 2; ++ks)
      #pragma unroll
      for (int m = 0; m < 8; ++m)
        #pragma unroll
        for (int n = 0; n < 3; ++n)
          acc[m][n] = __builtin_amdgcn_mfma_f32_16x16x32_bf16(af[m][ks], bfr[n][ks], acc[m][n], 0, 0, 0);
    __builtin_amdgcn_s_setprio(0);
  }

  const int a = lane & 15, hq = lane >> 4;
  #pragma unroll
  for (int m = 0; m < 8; ++m) {
    #pragma unroll
    for (int n = 0; n < 3; ++n) {
      int c = tN + wc * 48 + n * 16 + a;
      float bv = bias[c];
      int which = c >> 10;
      int cc = c & 1023, hh = cc >> 6, d = cc & 63;
      int row0 = tM + wr * 128 + m * 16 + hq * 4;
      int b = row0 >> 11, t0 = row0 & 2047;
      int bh = b * Hn + hh;
      if (which == 2) {
        ushort4 pk;
        pk.x = f2bf(acc[m][n][0] + bv);
        pk.y = f2bf(acc[m][n][1] + bv);
        pk.z = f2bf(acc[m][n][2] + bv);
        pk.w = f2bf(acc[m][n][3] + bv);
        *(ushort4*)&qkv[2 * PL + ((size_t)bh * HSn + d) * Tn + t0] = pk;
      } else {
        float sc = (which == 0) ? QSC : 1.0f;
        #pragma unroll
        for (int r = 0; r < 4; ++r) {
          float v = (acc[m][n][r] + bv) * sc;
          qkv[(size_t)which * PL + ((size_t)bh * Tn + t0 + r) * HSn + d] = f2bf(v);
        }
      }
    }
  }
}

// ---------------------------------------------------------------------------
// proj GEMM (R7 structure, XCD-swizzled flat grid 512)
// ---------------------------------------------------------------------------
template <int WM, int WN>
__global__ __launch_bounds__(256) void gemmP(
    const unsigned short* __restrict__ A, const unsigned short* __restrict__ Bt,
    const float* __restrict__ bias, float* __restrict__ O, int N, int K)
{
  constexpr int BM = WM * 32, BNt = WN * 32;
  constexpr int AF = BM / 16;
  constexpr int BF = BNt / 16;
  constexpr int NF = AF + BF;
  constexpr int PW = NF / 4;
  static_assert(PW == 3, "vmcnt literal");
  __shared__ alignas(16) unsigned char lds[2][NF * 1024];

  const int tid = threadIdx.x, wave = tid >> 6, lane = tid & 63;
  const int wr = wave >> 1, wc = wave & 1;
  const int orig = blockIdx.x;                        // 0..511
  const int swz = (orig & 7) * 64 + (orig >> 3);      // XCD: 64 contiguous
  const int bx = swz & 15, by = swz >> 4;             // 16 bx x 32 by
  const int tM = by * BM, tN = bx * BNt;

  auto STAGE = [&](int buf, int k0) {
    #pragma unroll
    for (int i = 0; i < PW; ++i) {
      int f = wave * PW + i;
      const unsigned short* g;
      if (f < AF)
        g = A + (size_t)(tM + f * 16 + (lane & 15)) * K + k0 + (lane >> 4) * 8;
      else
        g = Bt + (size_t)(tN + (f - AF) * 16 + (lane & 15)) * K + k0 + (lane >> 4) * 8;
      gload_lds16(g, &lds[buf][f * 1024]);
    }
  };

  f32x4 acc[WM][WN] = {};

  STAGE(0, 0);
  for (int t = 0, k0 = 0;; ++t, k0 += 32) {
    const int cur = t & 1;
    if (k0 + 32 < K) {
      STAGE(cur ^ 1, k0 + 32);
      asm volatile("s_waitcnt vmcnt(3)" ::: "memory");
    } else {
      asm volatile("s_waitcnt vmcnt(0)" ::: "memory");
    }
    __builtin_amdgcn_s_barrier();

    short8 af[WM], bfr[WN];
    #pragma unroll
    for (int m = 0; m < WM; ++m)
      af[m] = *(const short8*)&lds[cur][(wr * WM + m) * 1024 + lane * 16];
    #pragma unroll
    for (int n = 0; n < WN; ++n)
      bfr[n] = *(const short8*)&lds[cur][(AF + wc * WN + n) * 1024 + lane * 16];
    #pragma unroll
    for (int m = 0; m < WM; ++m)
      #pragma unroll
      for (int n = 0; n < WN; ++n)
        acc[m][n] = __builtin_amdgcn_mfma_f32_16x16x32_bf16(af[m], bfr[n], acc[m][n], 0, 0, 0);

    __builtin_amdgcn_s_barrier();
    if (k0 + 32 >= K) break;
  }

  const int a = lane & 15, hq = lane >> 4;
  #pragma unroll
  for (int m = 0; m < WM; ++m) {
    #pragma unroll
    for (int n = 0; n < WN; ++n) {
      int c = tN + wc * (WN * 16) + n * 16 + a;
      float bv = bias[c];
      int r0 = tM + wr * (WM * 16) + m * 16 + hq * 4;
      #pragma unroll
      for (int r = 0; r < 4; ++r)
        O[(size_t)(r0 + r) * N + c] = acc[m][n][r] + bv;
    }
  }
}

// ---------------------------------------------------------------------------
// Flash attention (R19/R21 best): KVBLK=64 double-buffered counted-vmcnt
// pipeline, uniform paired blocks (qt = yb and 31-yb -> 33 iters each),
// fixed-base softmax, l via ones-MFMA, XCD-swizzled flat grid 512.
// LDS 50176B: Q[0,8K) | K dbuf [8K,24K) | V dbuf [24K,40K) | P per-wave.
// ---------------------------------------------------------------------------
__global__ __launch_bounds__(256) void attn_mfma(
    const unsigned short* __restrict__ Qg, const unsigned short* __restrict__ Kg,
    const unsigned short* __restrict__ Vtg, unsigned short* __restrict__ Y)
{
  __shared__ alignas(16) unsigned char lds[50176];
  const int flat = blockIdx.x;                          // 0..511
  const int logical = (flat & 7) * 64 + (flat >> 3);    // XCD: 64 contiguous
  const int bh = logical >> 4;
  const int yb = logical & 15;                          // 0..15
  const int tid = threadIdx.x, wave = tid >> 6, lane = tid & 63;
  const int a = lane & 15, h = lane >> 4;
  const unsigned short* Qp = Qg + (size_t)bh * Tn * HSn;
  const unsigned short* Kp = Kg + (size_t)bh * Tn * HSn;
  const unsigned short* Vp = Vtg + (size_t)bh * HSn * Tn;   // [64][2048]
  const int pbase = 40960 + wave * 2304;
  const int qglob = wave * 16 + a;
  const int b = bh >> 4, hd = bh & 15;

  auto STAGE_K = [&](int kb, int kv0) {
    #pragma unroll
    for (int i = 0; i < 2; ++i) {
      int r8 = wave * 16 + i * 8;
      int row = r8 + (lane >> 3);
      int ch = (lane & 7) ^ (row & 7);
      gload_lds16(Kp + (size_t)(kv0 + row) * HSn + ch * 8,
                  &lds[8192 + kb * 8192 + r8 * 128]);
    }
  };
  auto STAGE_V = [&](int vb, int kv0) {
    #pragma unroll
    for (int i = 0; i < 2; ++i) {
      int r8 = wave * 16 + i * 8;
      int row = r8 + (lane >> 3);
      int ch = (lane & 7) ^ (row & 7);
      gload_lds16(Vp + (size_t)row * Tn + kv0 + ch * 8,
                  &lds[24576 + vb * 8192 + r8 * 128]);
    }
  };

  short8 ones;
  #pragma unroll
  for (int j = 0; j < 8; ++j) ones[j] = (short)0x3F80;    // bf16 1.0

  for (int ph = 0; ph < 2; ++ph) {
    const int qt = ph ? (31 - yb) : yb;
    const int q0 = qt * 64;

    #pragma unroll
    for (int i = 0; i < 2; ++i) {
      int r8 = wave * 16 + i * 8;
      int row = r8 + (lane >> 3);
      int ch = (lane & 7) ^ (row & 7);
      gload_lds16(Qp + (size_t)(q0 + row) * HSn + ch * 8, &lds[r8 * 128]);
    }
    STAGE_K(0, 0);
    STAGE_V(0, 0);
    if (qt >= 1) {
      STAGE_K(1, 64);
      STAGE_V(1, 64);
      asm volatile("s_waitcnt vmcnt(8)" ::: "memory");   // Q landed
    } else {
      asm volatile("s_waitcnt vmcnt(4)" ::: "memory");   // Q landed
    }

    short8 qf[2];
    #pragma unroll
    for (int ks = 0; ks < 2; ++ks) {
      int row = wave * 16 + a;
      int ch = (ks * 4 + h) ^ (row & 7);
      qf[ks] = *(const short8*)&lds[row * 128 + ch * 16];  // own wave's rows
    }

    f32x4 o[4] = {};
    f32x4 lacc = {};

    for (int t = 0; t <= qt; ++t) {
      const int kb = t & 1;
      if (t == qt)
        asm volatile("s_waitcnt vmcnt(0)" ::: "memory");
      else
        asm volatile("s_waitcnt vmcnt(4)" ::: "memory"); // tile t landed; t+1 in flight
      __builtin_amdgcn_s_barrier();

      const int kbase = 8192 + kb * 8192;
      const int vbase = 24576 + kb * 8192;

      f32x4 s[4] = {};
      __builtin_amdgcn_s_setprio(1);
      #pragma unroll
      for (int ks = 0; ks < 2; ++ks)
        #pragma unroll
        for (int n = 0; n < 4; ++n) {
          int kr = n * 16 + a;
          int ch = (ks * 4 + h) ^ (kr & 7);
          short8 kf = *(const short8*)&lds[kbase + kr * 128 + ch * 16];
          s[n] = __builtin_amdgcn_mfma_f32_16x16x32_bf16(kf, qf[ks], s[n], 0, 0, 0);
        }
      __builtin_amdgcn_s_setprio(0);

      if (t == qt) {
        #pragma unroll
        for (int n = 0; n < 4; ++n)
          #pragma unroll
          for (int r = 0; r < 4; ++r)
            if ((n * 16 + h * 4 + r) > qglob) s[n][r] = -1e30f;
      }

      #pragma unroll
      for (int n = 0; n < 4; ++n)
        #pragma unroll
        for (int r = 0; r < 4; ++r) s[n][r] = fexp2(s[n][r]);

      #pragma unroll
      for (int n = 0; n < 4; ++n) {
        uint2 w2;
        w2.x = (unsigned)f2bf(s[n][0]) | ((unsigned)f2bf(s[n][1]) << 16);
        w2.y = (unsigned)f2bf(s[n][2]) | ((unsigned)f2bf(s[n][3]) << 16);
        *(uint2*)&lds[pbase + (a * 36 + n * 8 + h * 2) * 4] = w2;
      }

      __builtin_amdgcn_s_setprio(1);
      #pragma unroll
      for (int ks = 0; ks < 2; ++ks) {
        short8 pa = *(const short8*)&lds[pbase + (a * 36 + ks * 16 + h * 4) * 4];
        lacc = __builtin_amdgcn_mfma_f32_16x16x32_bf16(pa, ones, lacc, 0, 0, 0);
        #pragma unroll
        for (int n = 0; n < 4; ++n) {
          int d = n * 16 + a;
          int ch = (ks * 4 + h) ^ (d & 7);
          short8 vf = *(const short8*)&lds[vbase + d * 128 + ch * 16];
          o[n] = __builtin_amdgcn_mfma_f32_16x16x32_bf16(pa, vf, o[n], 0, 0, 0);
        }
      }
      __builtin_amdgcn_s_setprio(0);

      __builtin_amdgcn_s_barrier();        // all waves done reading buf kb
      if (t + 2 <= qt) {
        STAGE_K(kb, (t + 2) * 64);         // lands during iter t+1
        STAGE_V(kb, (t + 2) * 64);
      }
    }

    f32x4 inv;
    #pragma unroll
    for (int r = 0; r < 4; ++r) inv[r] = 1.0f / lacc[r];
    #pragma unroll
    for (int n = 0; n < 4; ++n)
      #pragma unroll
      for (int r = 0; r < 4; ++r) {
        int tr = q0 + wave * 16 + 4 * h + r;
        int col = hd * 64 + n * 16 + a;
        Y[((size_t)(b * Tn + tr)) * Cn + col] = f2bf(o[n][r] * inv[r]);
      }
  }
}

// ---------------------------------------------------------------------------
extern "C" void kernel_launch(void* const* d_in, const int* in_sizes, int n_in,
                              void* d_out, int out_size, void* d_ws, size_t ws_size,
                              hipStream_t stream) {
  const float* x      = (const float*)d_in[0];
  const float* W_attn = (const float*)d_in[1];
  const float* b_attn = (const float*)d_in[2];
  const float* W_proj = (const float*)d_in[3];
  const float* b_proj = (const float*)d_in[4];
  float* out = (float*)d_out;

  unsigned short* xb  = (unsigned short*)d_ws;          // [4096][1024]
  unsigned short* Wab = xb + (size_t)Mrows * Cn;        // [3072][1024]
  unsigned short* Wpb = Wab + (size_t)3 * Cn * Cn;      // [1024][1024]
  unsigned short* qkv = Wpb + (size_t)Cn * Cn;          // 3 planes of PL
  unsigned short* y   = qkv + 3 * PL;                   // [4096][1024]

  prep_all<<<4096 + 3072 + 1024, 256, 0, stream>>>(x, xb, W_attn, Wab, W_proj, Wpb);

  // QKV: R15 winner — 256x192 tiles, 8 waves, grid 256, XCD-swizzled
  gemmQKV<<<256, 512, 0, stream>>>(xb, Wab, b_attn, qkv, Cn);

  // attn: R19 best — 64-KV pipeline, uniform paired blocks, XCD-swizzled
  attn_mfma<<<512, 256, 0, stream>>>(qkv, qkv + PL, qkv + 2 * PL, y);

  // proj: 128x64 tiles, XCD-swizzled flat grid 512
  gemmP<4, 2><<<512, 256, 0, stream>>>(y, Wpb, b_proj, out, Cn, Cn);
}